// Round 5
// baseline (437.512 us; speedup 1.0000x reference)
//
#include <hip/hip_runtime.h>
#include <hip/hip_bf16.h>

// out[b,s,e] = sum_d x[b,s,d] * kv[d,e],  kv[d,e] = sum_m keys[m,d]*vals[m,e]
// B*S = 8192, D = 1024, M = 65536. fp32 in/out; internal bf16 MFMA.
//
// Fast path (needs 260 MB ws):
//   1. convert_tile: fp32 [M][D] -> bf16 tiled "LDS-image" layout:
//        T[d_tile(8)][m_step(1024)][128 rows][64 m], XOR swizzle baked in.
//   2. kv_gemm: 128x128 tile, 2-deep LDS pipeline with COUNTED vmcnt(8)
//      (raw s_barrier, no vmcnt(0) in main loop), identity gl_lds from
//      contiguous 16KB tiles, swizzled ds_read, XCD-grouped tiles,
//      split-K 16, fp32 atomic reduce into kvw[e][d].
//   3. out_gemm: out[r][e] = sum_d x[r][d] * kvw[e][d]

typedef __attribute__((ext_vector_type(8))) __bf16 bf16x8;
typedef __attribute__((ext_vector_type(4))) __bf16 bf16x4;
typedef __attribute__((ext_vector_type(4))) float  f32x4;

#define D_DIM   1024
#define M_DIM   65536
#define ROWS    8192
#define NCHUNK  16
#define MC      (M_DIM / NCHUNK)   // 4096 m per chunk = 64 K-steps
#define BT      128
#define BK      64
#define LDK     72
#define TILE_BYTES 16384           // one [128][64] bf16 tile

__device__ __forceinline__ f32x4 mfma16(bf16x8 a, bf16x8 b, f32x4 c) {
    return __builtin_amdgcn_mfma_f32_16x16x32_bf16(a, b, c, 0, 0, 0);
}

__device__ __forceinline__ void gl_lds16(const void* gsrc, void* ldst) {
    __builtin_amdgcn_global_load_lds(
        (const __attribute__((address_space(1))) unsigned int*)gsrc,
        (__attribute__((address_space(3))) unsigned int*)ldst,
        16, 0, 0);
}

// ---------------------------------------------------------------------------
// Kernel A: fp32 [M][D] -> swizzled bf16 tiles (unchanged from R4).
// ---------------------------------------------------------------------------
__global__ __launch_bounds__(256)
void convert_tile(const float* __restrict__ keys,
                  const float* __restrict__ vals,
                  __hip_bfloat16* __restrict__ KtT,
                  __hip_bfloat16* __restrict__ VtT)
{
    __shared__ __bf16 Lt[128][72];

    const float* src = blockIdx.z ? vals : keys;
    char* dstb = (char*)(blockIdx.z ? VtT : KtT);

    const int tid = threadIdx.x;
    const int s  = blockIdx.x;        // m-step
    const int t  = blockIdx.y;        // d-tile
    const int m0 = s * 64;
    const int d0 = t * 128;

    #pragma unroll
    for (int i = 0; i < 8; ++i) {
        const int idx = tid + i * 256;
        const int mr  = idx >> 5;            // 0..63
        const int dc  = (idx & 31) * 4;      // 0..124
        f32x4 v = *(const f32x4*)(src + (size_t)(m0 + mr) * D_DIM + d0 + dc);
        #pragma unroll
        for (int j = 0; j < 4; ++j)
            Lt[dc + j][mr] = (__bf16)v[j];
    }
    __syncthreads();

    char* dst_tile = dstb + ((size_t)t * 1024 + s) * TILE_BYTES;
    #pragma unroll
    for (int r = 0; r < 4; ++r) {
        const int o  = r * 4096 + tid * 16;
        const int dl = o >> 7;
        const int c  = (o >> 4) & 7;
        const int cl = c ^ (dl & 7);
        bf16x8 w = *(const bf16x8*)&Lt[dl][cl * 8];
        *(bf16x8*)(dst_tile + o) = w;
    }
}

// ---------------------------------------------------------------------------
// Kernel B: kvw[e][d] += sum_m V[e][m] * K[d][m], tiled operands.
// 2-deep counted-vmcnt pipeline: stage(t+1) -> vmcnt(8) -> s_barrier ->
// compute buf[t&1] -> s_barrier.  Never drains vmcnt to 0 in the loop.
// ---------------------------------------------------------------------------
__global__ __launch_bounds__(256)
void kv_gemm(const __hip_bfloat16* __restrict__ VtT,
             const __hip_bfloat16* __restrict__ KtT,
             float* __restrict__ kvw)
{
    __shared__ __bf16 Va[2][128][64];
    __shared__ __bf16 Ka[2][128][64];

    const int tid  = threadIdx.x;
    const int lane = tid & 63;
    const int wave = tid >> 6;
    const int wr   = wave >> 1;      // e-half
    const int wc   = wave & 1;       // d-half

    // XCD-grouped tile remap: each XCD gets a 2(e) x 4(d) sub-block
    const int i64   = blockIdx.x & 63;
    const int chunk = blockIdx.x >> 6;
    const int xcd   = i64 & 7;
    const int slot  = i64 >> 3;
    const int e8 = (xcd >> 1) * 2 + (slot >> 2);
    const int d8 = (xcd & 1) * 4 + (slot & 3);

    const char* srcV = (const char*)VtT
        + ((size_t)e8 * 1024 + (size_t)chunk * 64) * TILE_BYTES
        + wave * 4096 + lane * 16;
    const char* srcK = (const char*)KtT
        + ((size_t)d8 * 1024 + (size_t)chunk * 64) * TILE_BYTES
        + wave * 4096 + lane * 16;

    f32x4 acc[4][4] = {};

    const int l15 = lane & 15;
    const int l7  = lane & 7;
    const int hi  = lane >> 4;

    auto stage = [&](int buf, int t) {
        const char* sv = srcV + (size_t)t * TILE_BYTES;
        const char* sk = srcK + (size_t)t * TILE_BYTES;
        char* dv = (char*)&Va[buf][0][0] + wave * 4096;
        char* dk = (char*)&Ka[buf][0][0] + wave * 4096;
        #pragma unroll
        for (int i = 0; i < 4; ++i) {
            gl_lds16(sv + i * 1024, dv + i * 1024);
            gl_lds16(sk + i * 1024, dk + i * 1024);
        }
    };

    stage(0, 0);   // prologue: tile 0 in flight (8 loads)

    for (int t = 0; t < 64; ++t) {
        if (t + 1 < 64) {
            stage((t + 1) & 1, t + 1);                   // 8 more loads in flight
            asm volatile("s_waitcnt vmcnt(8)" ::: "memory");  // tile t landed
        } else {
            asm volatile("s_waitcnt vmcnt(0)" ::: "memory");  // last tile
        }
        __builtin_amdgcn_s_barrier();   // all waves' tile-t rows visible

        const char* vbase = (const char*)&Va[t & 1][0][0];
        const char* kbase = (const char*)&Ka[t & 1][0][0];
        #pragma unroll
        for (int ks = 0; ks < BK; ks += 32) {
            bf16x8 af[4], bf[4];
            const int ca = (ks >> 3) + hi;           // logical chunk
            const int pc = (ca ^ l7) << 4;           // physical byte slot
            #pragma unroll
            for (int tt = 0; tt < 4; ++tt) {
                const int ra = wr * 64 + tt * 16 + l15;
                const int rb = wc * 64 + tt * 16 + l15;
                af[tt] = *(const bf16x8*)(vbase + ra * 128 + pc);
                bf[tt] = *(const bf16x8*)(kbase + rb * 128 + pc);
            }
            #pragma unroll
            for (int mi = 0; mi < 4; ++mi)
                #pragma unroll
                for (int ni = 0; ni < 4; ++ni)
                    acc[mi][ni] = mfma16(af[mi], bf[ni], acc[mi][ni]);
        }
        __builtin_amdgcn_s_barrier();   // all reads of buf[t&1] done -> next stage may overwrite
    }

    // epilogue: C row = V rows = e; col = K rows = d  (m89 map)
    const int rbase = (lane >> 4) * 4;
    const int cidx  = lane & 15;
    #pragma unroll
    for (int mi = 0; mi < 4; ++mi) {
        #pragma unroll
        for (int ni = 0; ni < 4; ++ni) {
            const int d = d8 * BT + wc * 64 + ni * 16 + cidx;
            #pragma unroll
            for (int reg = 0; reg < 4; ++reg) {
                const int e = e8 * BT + wr * 64 + mi * 16 + rbase + reg;
                atomicAdd(kvw + (size_t)e * D_DIM + d, acc[mi][ni][reg]);
            }
        }
    }
}

// ---------------------------------------------------------------------------
// Fallback (ws too small): R1 fused path, known-correct.
// ---------------------------------------------------------------------------
__global__ __launch_bounds__(256)
void kv_partial_kernel(const float* __restrict__ keys,
                       const float* __restrict__ vals,
                       float* __restrict__ kvw)
{
    __shared__ __bf16 Ktl[BT][LDK];
    __shared__ __bf16 Vtl[BT][LDK];

    const int tid  = threadIdx.x;
    const int lane = tid & 63;
    const int wave = tid >> 6;
    const int wr   = wave >> 1;
    const int wc   = wave & 1;

    const int tile  = blockIdx.x & 63;
    const int chunk = blockIdx.x >> 6;
    const int d0 = (tile >> 3) * BT;
    const int e0 = (tile & 7) * BT;
    const size_t mbeg = (size_t)chunk * MC;

    f32x4 acc[4][4] = {};
    const int kg  = tid & 15;
    const int d4a = tid >> 4;

    for (int ms = 0; ms < MC; ms += BK) {
        #pragma unroll
        for (int i = 0; i < 2; ++i) {
            const int dloc = (d4a + i * 16) * 4;
            const size_t mrow = mbeg + ms + (size_t)kg * 4;
            f32x4 kr[4], vr[4];
            #pragma unroll
            for (int r = 0; r < 4; ++r) {
                kr[r] = *(const f32x4*)(keys + (mrow + r) * D_DIM + d0 + dloc);
                vr[r] = *(const f32x4*)(vals + (mrow + r) * D_DIM + e0 + dloc);
            }
            #pragma unroll
            for (int j = 0; j < 4; ++j) {
                bf16x4 wk, wv;
                #pragma unroll
                for (int r = 0; r < 4; ++r) {
                    wk[r] = (__bf16)kr[r][j];
                    wv[r] = (__bf16)vr[r][j];
                }
                *(bf16x4*)&Ktl[dloc + j][kg * 4] = wk;
                *(bf16x4*)&Vtl[dloc + j][kg * 4] = wv;
            }
        }
        __syncthreads();

        #pragma unroll
        for (int ks = 0; ks < BK; ks += 32) {
            bf16x8 af[4], bf[4];
            #pragma unroll
            for (int t = 0; t < 4; ++t) {
                af[t] = *(const bf16x8*)&Ktl[wr * 64 + t * 16 + (lane & 15)][ks + (lane >> 4) * 8];
                bf[t] = *(const bf16x8*)&Vtl[wc * 64 + t * 16 + (lane & 15)][ks + (lane >> 4) * 8];
            }
            #pragma unroll
            for (int mi = 0; mi < 4; ++mi)
                #pragma unroll
                for (int ni = 0; ni < 4; ++ni)
                    acc[mi][ni] = mfma16(af[mi], bf[ni], acc[mi][ni]);
        }
        __syncthreads();
    }

    const int rbase = (lane >> 4) * 4;
    const int cidx  = lane & 15;
    #pragma unroll
    for (int mi = 0; mi < 4; ++mi) {
        #pragma unroll
        for (int ni = 0; ni < 4; ++ni) {
            const int e = e0 + wc * 64 + ni * 16 + cidx;
            #pragma unroll
            for (int reg = 0; reg < 4; ++reg) {
                const int d = d0 + wr * 64 + mi * 16 + rbase + reg;
                atomicAdd(kvw + (size_t)e * D_DIM + d, acc[mi][ni][reg]);
            }
        }
    }
}

// ---------------------------------------------------------------------------
// Kernel C: out[r][e] = sum_d x[r][d] * kvw[e][d]  (unchanged)
// ---------------------------------------------------------------------------
__global__ __launch_bounds__(256)
void out_gemm_kernel(const float* __restrict__ x,
                     const float* __restrict__ kvw,
                     float* __restrict__ out)
{
    __shared__ __bf16 Xt[BT][LDK];
    __shared__ __bf16 Wt[BT][LDK];

    const int tid  = threadIdx.x;
    const int lane = tid & 63;
    const int wave = tid >> 6;
    const int wr   = wave >> 1;
    const int wc   = wave & 1;

    const int r0 = blockIdx.x * BT;
    const int e0 = blockIdx.y * BT;

    f32x4 acc[4][4] = {};

    for (int ks0 = 0; ks0 < D_DIM; ks0 += BK) {
        #pragma unroll
        for (int i = 0; i < 8; ++i) {
            const int idx = tid + i * 256;
            const int row = idx >> 4;
            const int col = (idx & 15) * 4;
            f32x4 xa = *(const f32x4*)(x   + (size_t)(r0 + row) * D_DIM + ks0 + col);
            f32x4 wa = *(const f32x4*)(kvw + (size_t)(e0 + row) * D_DIM + ks0 + col);
            bf16x4 xb, wb;
            #pragma unroll
            for (int j = 0; j < 4; ++j) {
                xb[j] = (__bf16)xa[j];
                wb[j] = (__bf16)wa[j];
            }
            *(bf16x4*)&Xt[row][col] = xb;
            *(bf16x4*)&Wt[row][col] = wb;
        }
        __syncthreads();

        #pragma unroll
        for (int ks = 0; ks < BK; ks += 32) {
            bf16x8 af[4], bf[4];
            #pragma unroll
            for (int t = 0; t < 4; ++t) {
                af[t] = *(const bf16x8*)&Xt[wr * 64 + t * 16 + (lane & 15)][ks + (lane >> 4) * 8];
                bf[t] = *(const bf16x8*)&Wt[wc * 64 + t * 16 + (lane & 15)][ks + (lane >> 4) * 8];
            }
            #pragma unroll
            for (int mi = 0; mi < 4; ++mi)
                #pragma unroll
                for (int ni = 0; ni < 4; ++ni)
                    acc[mi][ni] = mfma16(af[mi], bf[ni], acc[mi][ni]);
        }
        __syncthreads();
    }

    const int rbase = (lane >> 4) * 4;
    const int cidx  = lane & 15;
    #pragma unroll
    for (int mi = 0; mi < 4; ++mi) {
        #pragma unroll
        for (int ni = 0; ni < 4; ++ni) {
            const int e = e0 + wc * 64 + ni * 16 + cidx;
            #pragma unroll
            for (int reg = 0; reg < 4; ++reg) {
                const int r = r0 + wr * 64 + mi * 16 + rbase + reg;
                out[(size_t)r * D_DIM + e] = acc[mi][ni][reg];
            }
        }
    }
}

extern "C" void kernel_launch(void* const* d_in, const int* in_sizes, int n_in,
                              void* d_out, int out_size, void* d_ws, size_t ws_size,
                              hipStream_t stream) {
    const float* x    = (const float*)d_in[0];
    const float* keys = (const float*)d_in[2];
    const float* vals = (const float*)d_in[3];
    float* out = (float*)d_out;

    const size_t kvw_bytes = (size_t)D_DIM * D_DIM * sizeof(float);          // 4 MiB
    const size_t kt_bytes  = (size_t)D_DIM * M_DIM * sizeof(__hip_bfloat16); // 128 MiB
    const size_t need      = kvw_bytes + 2 * kt_bytes;

    float* kvw = (float*)d_ws;
    hipMemsetAsync(kvw, 0, kvw_bytes, stream);

    if (ws_size >= need) {
        __hip_bfloat16* KtT = (__hip_bfloat16*)((char*)d_ws + kvw_bytes);
        __hip_bfloat16* VtT = (__hip_bfloat16*)((char*)d_ws + kvw_bytes + kt_bytes);
        convert_tile<<<dim3(M_DIM / 64, D_DIM / 128, 2), dim3(256), 0, stream>>>(
            keys, vals, KtT, VtT);
        kv_gemm<<<dim3(64 * NCHUNK), dim3(256), 0, stream>>>(VtT, KtT, kvw);
    } else {
        kv_partial_kernel<<<dim3(64 * NCHUNK), dim3(256), 0, stream>>>(keys, vals, kvw);
    }
    out_gemm_kernel<<<dim3(64, 8), dim3(256), 0, stream>>>(x, kvw, out);
}

// Round 6
// 366.878 us; speedup vs baseline: 1.1925x; 1.1925x over previous
//
#include <hip/hip_runtime.h>
#include <hip/hip_bf16.h>

// out[b,s,e] = sum_d x[b,s,d] * kv[d,e],  kv[d,e] = sum_m keys[m,d]*vals[m,e]
// B*S = 8192, D = 1024, M = 65536. fp32 in/out; internal bf16 MFMA.
//
// Fast path (needs 260 MB ws):
//   1. convert_tile: fp32 [M][D] -> bf16 tiled "LDS-image" layout
//        T[row_tile(8)][m_step(1024)][128 rows][64 m], XOR swizzle baked in.
//   2. kv_gemm8: 8-phase 256x256 schedule (T3+T4+T5), 512 thr / 8 waves,
//      BK=64, 2-slot 128KB LDS, gl_lds from contiguous 16KB tiles,
//      XCD-grouped split-K 16, fp32 atomic reduce into kvw[e][d].
//   3. out_gemm: out[r][e] = sum_d x[r][d] * kvw[e][d]

typedef __attribute__((ext_vector_type(8))) __bf16 bf16x8;
typedef __attribute__((ext_vector_type(4))) __bf16 bf16x4;
typedef __attribute__((ext_vector_type(4))) float  f32x4;

#define D_DIM   1024
#define M_DIM   65536
#define ROWS    8192
#define NCHUNK  16
#define MC      (M_DIM / NCHUNK)   // 4096 m per chunk = 64 K-tiles of 64
#define BT      128
#define BK      64
#define LDK     72
#define TILE_BYTES 16384           // one [128 rows][64 m] bf16 tile

__device__ __forceinline__ f32x4 mfma16(bf16x8 a, bf16x8 b, f32x4 c) {
    return __builtin_amdgcn_mfma_f32_16x16x32_bf16(a, b, c, 0, 0, 0);
}

__device__ __forceinline__ void gl_lds16(const void* gsrc, void* ldst) {
    __builtin_amdgcn_global_load_lds(
        (const __attribute__((address_space(1))) unsigned int*)gsrc,
        (__attribute__((address_space(3))) unsigned int*)ldst,
        16, 0, 0);
}

// ---------------------------------------------------------------------------
// Kernel A: fp32 [M][D] -> swizzled bf16 tiles (unchanged from R4/R5).
// ---------------------------------------------------------------------------
__global__ __launch_bounds__(256)
void convert_tile(const float* __restrict__ keys,
                  const float* __restrict__ vals,
                  __hip_bfloat16* __restrict__ KtT,
                  __hip_bfloat16* __restrict__ VtT)
{
    __shared__ __bf16 Lt[128][72];

    const float* src = blockIdx.z ? vals : keys;
    char* dstb = (char*)(blockIdx.z ? VtT : KtT);

    const int tid = threadIdx.x;
    const int s  = blockIdx.x;        // m-step
    const int t  = blockIdx.y;        // row-tile
    const int m0 = s * 64;
    const int d0 = t * 128;

    #pragma unroll
    for (int i = 0; i < 8; ++i) {
        const int idx = tid + i * 256;
        const int mr  = idx >> 5;            // 0..63
        const int dc  = (idx & 31) * 4;      // 0..124
        f32x4 v = *(const f32x4*)(src + (size_t)(m0 + mr) * D_DIM + d0 + dc);
        #pragma unroll
        for (int j = 0; j < 4; ++j)
            Lt[dc + j][mr] = (__bf16)v[j];
    }
    __syncthreads();

    char* dst_tile = dstb + ((size_t)t * 1024 + s) * TILE_BYTES;
    #pragma unroll
    for (int r = 0; r < 4; ++r) {
        const int o  = r * 4096 + tid * 16;
        const int dl = o >> 7;
        const int c  = (o >> 4) & 7;
        const int cl = c ^ (dl & 7);
        bf16x8 w = *(const bf16x8*)&Lt[dl][cl * 8];
        *(bf16x8*)(dst_tile + o) = w;
    }
}

// ---------------------------------------------------------------------------
// Kernel B: kvw[e][d] += sum_m V[e][m] * K[d][m], tiled operands.
// 8-phase 256x256 template: 8 waves (2e x 4d), 4 phases per BK=64 K-tile,
// per phase {ds_read frags | stage sub-tile -> barrier -> lgkmcnt(0) ->
// setprio(1) 16 MFMA setprio(0) -> barrier}, vmcnt(0) only at tile boundary.
// ---------------------------------------------------------------------------
__global__ __launch_bounds__(512, 2)
void kv_gemm8(const __hip_bfloat16* __restrict__ VtT,
              const __hip_bfloat16* __restrict__ KtT,
              float* __restrict__ kvw)
{
    // [slot][subtile: 0=A-lo 1=A-hi 2=B-lo 3=B-hi][16KB]
    __shared__ __align__(16) char lds[2][4][TILE_BYTES];

    const int tid  = threadIdx.x;
    const int lane = tid & 63;
    const int wave = tid >> 6;        // 0..7
    const int we   = wave >> 2;       // 0..1  e-dim (A half)
    const int wd   = wave & 3;        // 0..3  d-dim

    // XCD-bijective map: 256 blocks, xcd = bx&7 owns 2 chunks x 16 tiles
    const int bx    = blockIdx.x;
    const int xcd   = bx & 7;
    const int idx   = bx >> 3;                 // 0..31
    const int chunk = ((idx >> 4) << 3) | xcd; // 0..15
    const int t16   = idx & 15;
    const int E8    = t16 >> 2;                // 0..3 (256-row e-tile)
    const int D8    = t16 & 3;                 // 0..3 (256-row d-tile)

    const size_t step0 = (size_t)chunk * 64;   // first m-step of this chunk

    const char* Vb = (const char*)VtT;
    const char* Kb = (const char*)KtT;

    const int l15 = lane & 15;
    const int l7  = lane & 7;
    const int hi  = lane >> 4;

    f32x4 acc[8][4] = {};

    auto tileptr = [&](const char* base, int rt, int t) -> const char* {
        return base + ((size_t)rt * 1024 + step0 + (size_t)t) * TILE_BYTES;
    };
    auto stage_sub = [&](int buf, int sub, const char* tile) {
        char* dst = &lds[buf][sub][wave * 1024];
        const char* s = tile + wave * 1024 + lane * 16;
        gl_lds16(s,        dst);
        gl_lds16(s + 8192, dst + 8192);
    };

    // prologue: tile 0 into slot 0
    stage_sub(0, 0, tileptr(Vb, 2 * E8,     0));
    stage_sub(0, 1, tileptr(Vb, 2 * E8 + 1, 0));
    stage_sub(0, 2, tileptr(Kb, 2 * D8,     0));
    stage_sub(0, 3, tileptr(Kb, 2 * D8 + 1, 0));
    asm volatile("s_waitcnt vmcnt(0)" ::: "memory");
    __builtin_amdgcn_s_barrier();

    bf16x8 bfr[4][2];   // B frags persist across the 4 phases of a tile

    #pragma unroll 2
    for (int t = 0; t < 64; ++t) {
        const int buf = t & 1;
        const char* abase = &lds[buf][we][0];
        const char* bbase = &lds[buf][2 + (wd >> 1)][0];
        const int brow0 = (wd & 1) * 64;

        #pragma unroll
        for (int p = 0; p < 4; ++p) {
            // ---- ds_read this phase's A frags (2 m-rows x 2 ks) ----
            bf16x8 afr[2][2];
            #pragma unroll
            for (int j = 0; j < 2; ++j)
                #pragma unroll
                for (int ks = 0; ks < 2; ++ks) {
                    const int row = (2 * p + j) * 16 + l15;
                    afr[j][ks] = *(const bf16x8*)(abase + row * 128
                                   + (((ks << 2) + hi) ^ l7) * 16);
                }
            if (p == 0) {   // all B frags once per tile
                #pragma unroll
                for (int n = 0; n < 4; ++n)
                    #pragma unroll
                    for (int ks = 0; ks < 2; ++ks) {
                        const int row = brow0 + n * 16 + l15;
                        bfr[n][ks] = *(const bf16x8*)(bbase + row * 128
                                       + (((ks << 2) + hi) ^ l7) * 16);
                    }
            }
            // ---- stage next tile early (phases 0,1) ----
            if (p == 0 && t + 1 < 64) {
                stage_sub(buf ^ 1, 0, tileptr(Vb, 2 * E8,     t + 1));
                stage_sub(buf ^ 1, 1, tileptr(Vb, 2 * E8 + 1, t + 1));
            }
            if (p == 1 && t + 1 < 64) {
                stage_sub(buf ^ 1, 2, tileptr(Kb, 2 * D8,     t + 1));
                stage_sub(buf ^ 1, 3, tileptr(Kb, 2 * D8 + 1, t + 1));
            }
            __builtin_amdgcn_s_barrier();
            asm volatile("s_waitcnt lgkmcnt(0)" ::: "memory");
            __builtin_amdgcn_sched_barrier(0);
            __builtin_amdgcn_s_setprio(1);
            #pragma unroll
            for (int j = 0; j < 2; ++j)
                #pragma unroll
                for (int n = 0; n < 4; ++n)
                    #pragma unroll
                    for (int ks = 0; ks < 2; ++ks)
                        acc[2 * p + j][n] = mfma16(afr[j][ks], bfr[n][ks],
                                                   acc[2 * p + j][n]);
            __builtin_amdgcn_s_setprio(0);
            if (p == 3)   // next tile's 8 stages (issued ph0-1) must land
                asm volatile("s_waitcnt vmcnt(0)" ::: "memory");
            __builtin_amdgcn_s_barrier();
        }
    }

    // epilogue: C row = V rows = e; col = K rows = d  (m89 map)
    const int rb = hi * 4;
    #pragma unroll
    for (int mi = 0; mi < 8; ++mi) {
        #pragma unroll
        for (int ni = 0; ni < 4; ++ni) {
            const int d = D8 * 256 + wd * 64 + ni * 16 + l15;
            #pragma unroll
            for (int r = 0; r < 4; ++r) {
                const int e = E8 * 256 + we * 128 + mi * 16 + rb + r;
                atomicAdd(kvw + (size_t)e * D_DIM + d, acc[mi][ni][r]);
            }
        }
    }
}

// ---------------------------------------------------------------------------
// Fallback (ws too small): R1 fused path, known-correct.
// ---------------------------------------------------------------------------
__global__ __launch_bounds__(256)
void kv_partial_kernel(const float* __restrict__ keys,
                       const float* __restrict__ vals,
                       float* __restrict__ kvw)
{
    __shared__ __bf16 Ktl[BT][LDK];
    __shared__ __bf16 Vtl[BT][LDK];

    const int tid  = threadIdx.x;
    const int lane = tid & 63;
    const int wave = tid >> 6;
    const int wr   = wave >> 1;
    const int wc   = wave & 1;

    const int tile  = blockIdx.x & 63;
    const int chunk = blockIdx.x >> 6;
    const int d0 = (tile >> 3) * BT;
    const int e0 = (tile & 7) * BT;
    const size_t mbeg = (size_t)chunk * MC;

    f32x4 acc[4][4] = {};
    const int kg  = tid & 15;
    const int d4a = tid >> 4;

    for (int ms = 0; ms < MC; ms += BK) {
        #pragma unroll
        for (int i = 0; i < 2; ++i) {
            const int dloc = (d4a + i * 16) * 4;
            const size_t mrow = mbeg + ms + (size_t)kg * 4;
            f32x4 kr[4], vr[4];
            #pragma unroll
            for (int r = 0; r < 4; ++r) {
                kr[r] = *(const f32x4*)(keys + (mrow + r) * D_DIM + d0 + dloc);
                vr[r] = *(const f32x4*)(vals + (mrow + r) * D_DIM + e0 + dloc);
            }
            #pragma unroll
            for (int j = 0; j < 4; ++j) {
                bf16x4 wk, wv;
                #pragma unroll
                for (int r = 0; r < 4; ++r) {
                    wk[r] = (__bf16)kr[r][j];
                    wv[r] = (__bf16)vr[r][j];
                }
                *(bf16x4*)&Ktl[dloc + j][kg * 4] = wk;
                *(bf16x4*)&Vtl[dloc + j][kg * 4] = wv;
            }
        }
        __syncthreads();

        #pragma unroll
        for (int ks = 0; ks < BK; ks += 32) {
            bf16x8 af[4], bf[4];
            #pragma unroll
            for (int t = 0; t < 4; ++t) {
                af[t] = *(const bf16x8*)&Ktl[wr * 64 + t * 16 + (lane & 15)][ks + (lane >> 4) * 8];
                bf[t] = *(const bf16x8*)&Vtl[wc * 64 + t * 16 + (lane & 15)][ks + (lane >> 4) * 8];
            }
            #pragma unroll
            for (int mi = 0; mi < 4; ++mi)
                #pragma unroll
                for (int ni = 0; ni < 4; ++ni)
                    acc[mi][ni] = mfma16(af[mi], bf[ni], acc[mi][ni]);
        }
        __syncthreads();
    }

    const int rbase = (lane >> 4) * 4;
    const int cidx  = lane & 15;
    #pragma unroll
    for (int mi = 0; mi < 4; ++mi) {
        #pragma unroll
        for (int ni = 0; ni < 4; ++ni) {
            const int e = e0 + wc * 64 + ni * 16 + cidx;
            #pragma unroll
            for (int reg = 0; reg < 4; ++reg) {
                const int d = d0 + wr * 64 + mi * 16 + rbase + reg;
                atomicAdd(kvw + (size_t)e * D_DIM + d, acc[mi][ni][reg]);
            }
        }
    }
}

// ---------------------------------------------------------------------------
// Kernel C: out[r][e] = sum_d x[r][d] * kvw[e][d]  (unchanged)
// ---------------------------------------------------------------------------
__global__ __launch_bounds__(256)
void out_gemm_kernel(const float* __restrict__ x,
                     const float* __restrict__ kvw,
                     float* __restrict__ out)
{
    __shared__ __bf16 Xt[BT][LDK];
    __shared__ __bf16 Wt[BT][LDK];

    const int tid  = threadIdx.x;
    const int lane = tid & 63;
    const int wave = tid >> 6;
    const int wr   = wave >> 1;
    const int wc   = wave & 1;

    const int r0 = blockIdx.x * BT;
    const int e0 = blockIdx.y * BT;

    f32x4 acc[4][4] = {};

    for (int ks0 = 0; ks0 < D_DIM; ks0 += BK) {
        #pragma unroll
        for (int i = 0; i < 8; ++i) {
            const int idx = tid + i * 256;
            const int row = idx >> 4;
            const int col = (idx & 15) * 4;
            f32x4 xa = *(const f32x4*)(x   + (size_t)(r0 + row) * D_DIM + ks0 + col);
            f32x4 wa = *(const f32x4*)(kvw + (size_t)(e0 + row) * D_DIM + ks0 + col);
            bf16x4 xb, wb;
            #pragma unroll
            for (int j = 0; j < 4; ++j) {
                xb[j] = (__bf16)xa[j];
                wb[j] = (__bf16)wa[j];
            }
            *(bf16x4*)&Xt[row][col] = xb;
            *(bf16x4*)&Wt[row][col] = wb;
        }
        __syncthreads();

        #pragma unroll
        for (int ks = 0; ks < BK; ks += 32) {
            bf16x8 af[4], bf[4];
            #pragma unroll
            for (int t = 0; t < 4; ++t) {
                af[t] = *(const bf16x8*)&Xt[wr * 64 + t * 16 + (lane & 15)][ks + (lane >> 4) * 8];
                bf[t] = *(const bf16x8*)&Wt[wc * 64 + t * 16 + (lane & 15)][ks + (lane >> 4) * 8];
            }
            #pragma unroll
            for (int mi = 0; mi < 4; ++mi)
                #pragma unroll
                for (int ni = 0; ni < 4; ++ni)
                    acc[mi][ni] = mfma16(af[mi], bf[ni], acc[mi][ni]);
        }
        __syncthreads();
    }

    const int rbase = (lane >> 4) * 4;
    const int cidx  = lane & 15;
    #pragma unroll
    for (int mi = 0; mi < 4; ++mi) {
        #pragma unroll
        for (int ni = 0; ni < 4; ++ni) {
            const int e = e0 + wc * 64 + ni * 16 + cidx;
            #pragma unroll
            for (int reg = 0; reg < 4; ++reg) {
                const int r = r0 + wr * 64 + mi * 16 + rbase + reg;
                out[(size_t)r * D_DIM + e] = acc[mi][ni][reg];
            }
        }
    }
}

extern "C" void kernel_launch(void* const* d_in, const int* in_sizes, int n_in,
                              void* d_out, int out_size, void* d_ws, size_t ws_size,
                              hipStream_t stream) {
    const float* x    = (const float*)d_in[0];
    const float* keys = (const float*)d_in[2];
    const float* vals = (const float*)d_in[3];
    float* out = (float*)d_out;

    const size_t kvw_bytes = (size_t)D_DIM * D_DIM * sizeof(float);          // 4 MiB
    const size_t kt_bytes  = (size_t)D_DIM * M_DIM * sizeof(__hip_bfloat16); // 128 MiB
    const size_t need      = kvw_bytes + 2 * kt_bytes;

    float* kvw = (float*)d_ws;
    hipMemsetAsync(kvw, 0, kvw_bytes, stream);

    if (ws_size >= need) {
        __hip_bfloat16* KtT = (__hip_bfloat16*)((char*)d_ws + kvw_bytes);
        __hip_bfloat16* VtT = (__hip_bfloat16*)((char*)d_ws + kvw_bytes + kt_bytes);
        convert_tile<<<dim3(M_DIM / 64, D_DIM / 128, 2), dim3(256), 0, stream>>>(
            keys, vals, KtT, VtT);
        kv_gemm8<<<dim3(256), dim3(512), 0, stream>>>(VtT, KtT, kvw);
    } else {
        kv_partial_kernel<<<dim3(64 * NCHUNK), dim3(256), 0, stream>>>(keys, vals, kvw);
    }
    out_gemm_kernel<<<dim3(64, 8), dim3(256), 0, stream>>>(x, kvw, out);
}

// Round 7
// 364.812 us; speedup vs baseline: 1.1993x; 1.0057x over previous
//
#include <hip/hip_runtime.h>
#include <hip/hip_bf16.h>

// out[b,s,e] = sum_d x[b,s,d] * kv[d,e],  kv[d,e] = sum_m keys[m,d]*vals[m,e]
// B*S = 8192, D = 1024, M = 65536. fp32 in/out; internal bf16 MFMA.
//
// Fast path (needs 260 MB ws):
//   1. convert_tile: fp32 [M][D] -> bf16 tiled "LDS-image" layout
//        T[row_tile(8)][m_step(1024)][128 rows][64 m], XOR chunk-swizzle
//        (cl = c ^ (row&7)) baked in.  Bank-engineered: 8B LDS ops both
//        phases, granule swizzle p8 = q ^ ((row>>2)&15) -> 0 conflicts.
//   2. kv_gemm8: 8-phase 256x256 schedule (T3+T4+T5), 512 thr / 8 waves,
//      BK=64, 2-slot 128KB LDS, gl_lds from contiguous 16KB tiles,
//      XCD-grouped split-K 16, fp32 atomic reduce into kvw[e][d].
//   3. out_gemm: out[r][e] = sum_d x[r][d] * kvw[e][d]

typedef __attribute__((ext_vector_type(8))) __bf16 bf16x8;
typedef __attribute__((ext_vector_type(4))) __bf16 bf16x4;
typedef __attribute__((ext_vector_type(4))) float  f32x4;

#define D_DIM   1024
#define M_DIM   65536
#define ROWS    8192
#define NCHUNK  16
#define MC      (M_DIM / NCHUNK)   // 4096 m per chunk = 64 K-tiles of 64
#define BT      128
#define BK      64
#define LDK     72
#define TILE_BYTES 16384           // one [128 rows][64 m] bf16 tile

__device__ __forceinline__ f32x4 mfma16(bf16x8 a, bf16x8 b, f32x4 c) {
    return __builtin_amdgcn_mfma_f32_16x16x32_bf16(a, b, c, 0, 0, 0);
}

__device__ __forceinline__ void gl_lds16(const void* gsrc, void* ldst) {
    __builtin_amdgcn_global_load_lds(
        (const __attribute__((address_space(1))) unsigned int*)gsrc,
        (__attribute__((address_space(3))) unsigned int*)ldst,
        16, 0, 0);
}

// ---------------------------------------------------------------------------
// Kernel A: fp32 [M][D] -> swizzled bf16 tiles.  Bank-engineered rewrite.
// Block: 64 m x 128 d.  grid = (1024 m-steps, 8 row-tiles, 2 {keys,vals}).
// LDS logical layout: row = d_local (128 rows, stride 144B), row content =
// 16 8B granules; granule q holds m-quad 4q..4q+3; physical granule =
// q ^ ((row>>2)&15).
// ---------------------------------------------------------------------------
__global__ __launch_bounds__(256)
void convert_tile(const float* __restrict__ keys,
                  const float* __restrict__ vals,
                  __hip_bfloat16* __restrict__ KtT,
                  __hip_bfloat16* __restrict__ VtT)
{
    __shared__ __align__(16) char Lt[128 * 144];   // 18432 B

    const float* src = blockIdx.z ? vals : keys;
    char* dstb = (char*)(blockIdx.z ? VtT : KtT);

    const int tid = threadIdx.x;
    const int s  = blockIdx.x;        // m-step (64 m)
    const int t  = blockIdx.y;        // row-tile (128 d)
    const int m0 = s * 64;
    const int d0 = t * 128;

    // ---- phase 1: coalesced fp32 read, in-reg transpose, swizzled 8B writes
    const int dc = tid & 31;          // d-chunk (4 d)
    #pragma unroll
    for (int i = 0; i < 2; ++i) {
        const int q = (tid >> 5) + 8 * i;     // m-quad 0..15
        f32x4 v[4];
        #pragma unroll
        for (int r = 0; r < 4; ++r)
            v[r] = *(const f32x4*)(src + (size_t)(m0 + 4 * q + r) * D_DIM + d0 + 4 * dc);
        #pragma unroll
        for (int j = 0; j < 4; ++j) {
            bf16x4 w;
            #pragma unroll
            for (int r = 0; r < 4; ++r) w[r] = (__bf16)v[r][j];
            const int row = 4 * dc + j;
            const int p8  = q ^ (dc & 15);    // phys granule = q ^ ((row>>2)&15)
            *(bf16x4*)(Lt + row * 144 + p8 * 8) = w;
        }
    }
    __syncthreads();

    // ---- phase 2: swizzle-resolving 8B reads, coalesced 16B global writes
    char* dst_tile = dstb + ((size_t)t * 1024 + s) * TILE_BYTES;
    #pragma unroll
    for (int p = 0; p < 4; ++p) {
        const int dl = p * 32 + (tid >> 3);   // 0..127
        const int c  = tid & 7;               // phys output chunk
        const int cl = c ^ (dl & 7);          // logical chunk (output swizzle)
        const int h  = (dl >> 2) & 15;
        const int g0 = (2 * cl)     ^ h;      // phys granules of logical {2cl,2cl+1}
        const int g1 = (2 * cl + 1) ^ h;
        bf16x4 lo = *(const bf16x4*)(Lt + dl * 144 + g0 * 8);
        bf16x4 hi = *(const bf16x4*)(Lt + dl * 144 + g1 * 8);
        bf16x8 w;
        w[0] = lo[0]; w[1] = lo[1]; w[2] = lo[2]; w[3] = lo[3];
        w[4] = hi[0]; w[5] = hi[1]; w[6] = hi[2]; w[7] = hi[3];
        *(bf16x8*)(dst_tile + dl * 128 + c * 16) = w;
    }
}

// ---------------------------------------------------------------------------
// Kernel B: kvw[e][d] += sum_m V[e][m] * K[d][m], tiled operands.
// 8-phase 256x256 template (unchanged from R6).
// ---------------------------------------------------------------------------
__global__ __launch_bounds__(512, 2)
void kv_gemm8(const __hip_bfloat16* __restrict__ VtT,
              const __hip_bfloat16* __restrict__ KtT,
              float* __restrict__ kvw)
{
    __shared__ __align__(16) char lds[2][4][TILE_BYTES];

    const int tid  = threadIdx.x;
    const int lane = tid & 63;
    const int wave = tid >> 6;        // 0..7
    const int we   = wave >> 2;       // 0..1  e-dim (A half)
    const int wd   = wave & 3;        // 0..3  d-dim

    const int bx    = blockIdx.x;
    const int xcd   = bx & 7;
    const int idx   = bx >> 3;                 // 0..31
    const int chunk = ((idx >> 4) << 3) | xcd; // 0..15
    const int t16   = idx & 15;
    const int E8    = t16 >> 2;                // 0..3
    const int D8    = t16 & 3;                 // 0..3

    const size_t step0 = (size_t)chunk * 64;

    const char* Vb = (const char*)VtT;
    const char* Kb = (const char*)KtT;

    const int l15 = lane & 15;
    const int l7  = lane & 7;
    const int hi  = lane >> 4;

    f32x4 acc[8][4] = {};

    auto tileptr = [&](const char* base, int rt, int t) -> const char* {
        return base + ((size_t)rt * 1024 + step0 + (size_t)t) * TILE_BYTES;
    };
    auto stage_sub = [&](int buf, int sub, const char* tile) {
        char* dst = &lds[buf][sub][wave * 1024];
        const char* s = tile + wave * 1024 + lane * 16;
        gl_lds16(s,        dst);
        gl_lds16(s + 8192, dst + 8192);
    };

    stage_sub(0, 0, tileptr(Vb, 2 * E8,     0));
    stage_sub(0, 1, tileptr(Vb, 2 * E8 + 1, 0));
    stage_sub(0, 2, tileptr(Kb, 2 * D8,     0));
    stage_sub(0, 3, tileptr(Kb, 2 * D8 + 1, 0));
    asm volatile("s_waitcnt vmcnt(0)" ::: "memory");
    __builtin_amdgcn_s_barrier();

    bf16x8 bfr[4][2];

    #pragma unroll 2
    for (int t = 0; t < 64; ++t) {
        const int buf = t & 1;
        const char* abase = &lds[buf][we][0];
        const char* bbase = &lds[buf][2 + (wd >> 1)][0];
        const int brow0 = (wd & 1) * 64;

        #pragma unroll
        for (int p = 0; p < 4; ++p) {
            bf16x8 afr[2][2];
            #pragma unroll
            for (int j = 0; j < 2; ++j)
                #pragma unroll
                for (int ks = 0; ks < 2; ++ks) {
                    const int row = (2 * p + j) * 16 + l15;
                    afr[j][ks] = *(const bf16x8*)(abase + row * 128
                                   + (((ks << 2) + hi) ^ l7) * 16);
                }
            if (p == 0) {
                #pragma unroll
                for (int n = 0; n < 4; ++n)
                    #pragma unroll
                    for (int ks = 0; ks < 2; ++ks) {
                        const int row = brow0 + n * 16 + l15;
                        bfr[n][ks] = *(const bf16x8*)(bbase + row * 128
                                       + (((ks << 2) + hi) ^ l7) * 16);
                    }
            }
            if (p == 0 && t + 1 < 64) {
                stage_sub(buf ^ 1, 0, tileptr(Vb, 2 * E8,     t + 1));
                stage_sub(buf ^ 1, 1, tileptr(Vb, 2 * E8 + 1, t + 1));
            }
            if (p == 1 && t + 1 < 64) {
                stage_sub(buf ^ 1, 2, tileptr(Kb, 2 * D8,     t + 1));
                stage_sub(buf ^ 1, 3, tileptr(Kb, 2 * D8 + 1, t + 1));
            }
            __builtin_amdgcn_s_barrier();
            asm volatile("s_waitcnt lgkmcnt(0)" ::: "memory");
            __builtin_amdgcn_sched_barrier(0);
            __builtin_amdgcn_s_setprio(1);
            #pragma unroll
            for (int j = 0; j < 2; ++j)
                #pragma unroll
                for (int n = 0; n < 4; ++n)
                    #pragma unroll
                    for (int ks = 0; ks < 2; ++ks)
                        acc[2 * p + j][n] = mfma16(afr[j][ks], bfr[n][ks],
                                                   acc[2 * p + j][n]);
            __builtin_amdgcn_s_setprio(0);
            if (p == 3)
                asm volatile("s_waitcnt vmcnt(0)" ::: "memory");
            __builtin_amdgcn_s_barrier();
        }
    }

    const int rb = hi * 4;
    #pragma unroll
    for (int mi = 0; mi < 8; ++mi) {
        #pragma unroll
        for (int ni = 0; ni < 4; ++ni) {
            const int d = D8 * 256 + wd * 64 + ni * 16 + l15;
            #pragma unroll
            for (int r = 0; r < 4; ++r) {
                const int e = E8 * 256 + we * 128 + mi * 16 + rb + r;
                atomicAdd(kvw + (size_t)e * D_DIM + d, acc[mi][ni][r]);
            }
        }
    }
}

// ---------------------------------------------------------------------------
// Fallback (ws too small): R1 fused path, known-correct.
// ---------------------------------------------------------------------------
__global__ __launch_bounds__(256)
void kv_partial_kernel(const float* __restrict__ keys,
                       const float* __restrict__ vals,
                       float* __restrict__ kvw)
{
    __shared__ __bf16 Ktl[BT][LDK];
    __shared__ __bf16 Vtl[BT][LDK];

    const int tid  = threadIdx.x;
    const int lane = tid & 63;
    const int wave = tid >> 6;
    const int wr   = wave >> 1;
    const int wc   = wave & 1;

    const int tile  = blockIdx.x & 63;
    const int chunk = blockIdx.x >> 6;
    const int d0 = (tile >> 3) * BT;
    const int e0 = (tile & 7) * BT;
    const size_t mbeg = (size_t)chunk * MC;

    f32x4 acc[4][4] = {};
    const int kg  = tid & 15;
    const int d4a = tid >> 4;

    for (int ms = 0; ms < MC; ms += BK) {
        #pragma unroll
        for (int i = 0; i < 2; ++i) {
            const int dloc = (d4a + i * 16) * 4;
            const size_t mrow = mbeg + ms + (size_t)kg * 4;
            f32x4 kr[4], vr[4];
            #pragma unroll
            for (int r = 0; r < 4; ++r) {
                kr[r] = *(const f32x4*)(keys + (mrow + r) * D_DIM + d0 + dloc);
                vr[r] = *(const f32x4*)(vals + (mrow + r) * D_DIM + e0 + dloc);
            }
            #pragma unroll
            for (int j = 0; j < 4; ++j) {
                bf16x4 wk, wv;
                #pragma unroll
                for (int r = 0; r < 4; ++r) {
                    wk[r] = (__bf16)kr[r][j];
                    wv[r] = (__bf16)vr[r][j];
                }
                *(bf16x4*)&Ktl[dloc + j][kg * 4] = wk;
                *(bf16x4*)&Vtl[dloc + j][kg * 4] = wv;
            }
        }
        __syncthreads();

        #pragma unroll
        for (int ks = 0; ks < BK; ks += 32) {
            bf16x8 af[4], bf[4];
            #pragma unroll
            for (int t = 0; t < 4; ++t) {
                af[t] = *(const bf16x8*)&Ktl[wr * 64 + t * 16 + (lane & 15)][ks + (lane >> 4) * 8];
                bf[t] = *(const bf16x8*)&Vtl[wc * 64 + t * 16 + (lane & 15)][ks + (lane >> 4) * 8];
            }
            #pragma unroll
            for (int mi = 0; mi < 4; ++mi)
                #pragma unroll
                for (int ni = 0; ni < 4; ++ni)
                    acc[mi][ni] = mfma16(af[mi], bf[ni], acc[mi][ni]);
        }
        __syncthreads();
    }

    const int rbase = (lane >> 4) * 4;
    const int cidx  = lane & 15;
    #pragma unroll
    for (int mi = 0; mi < 4; ++mi) {
        #pragma unroll
        for (int ni = 0; ni < 4; ++ni) {
            const int e = e0 + wc * 64 + ni * 16 + cidx;
            #pragma unroll
            for (int reg = 0; reg < 4; ++reg) {
                const int d = d0 + wr * 64 + mi * 16 + rbase + reg;
                atomicAdd(kvw + (size_t)e * D_DIM + d, acc[mi][ni][reg]);
            }
        }
    }
}

// ---------------------------------------------------------------------------
// Kernel C: out[r][e] = sum_d x[r][d] * kvw[e][d]  (unchanged)
// ---------------------------------------------------------------------------
__global__ __launch_bounds__(256)
void out_gemm_kernel(const float* __restrict__ x,
                     const float* __restrict__ kvw,
                     float* __restrict__ out)
{
    __shared__ __bf16 Xt[BT][LDK];
    __shared__ __bf16 Wt[BT][LDK];

    const int tid  = threadIdx.x;
    const int lane = tid & 63;
    const int wave = tid >> 6;
    const int wr   = wave >> 1;
    const int wc   = wave & 1;

    const int r0 = blockIdx.x * BT;
    const int e0 = blockIdx.y * BT;

    f32x4 acc[4][4] = {};

    for (int ks0 = 0; ks0 < D_DIM; ks0 += BK) {
        #pragma unroll
        for (int i = 0; i < 8; ++i) {
            const int idx = tid + i * 256;
            const int row = idx >> 4;
            const int col = (idx & 15) * 4;
            f32x4 xa = *(const f32x4*)(x   + (size_t)(r0 + row) * D_DIM + ks0 + col);
            f32x4 wa = *(const f32x4*)(kvw + (size_t)(e0 + row) * D_DIM + ks0 + col);
            bf16x4 xb, wb;
            #pragma unroll
            for (int j = 0; j < 4; ++j) {
                xb[j] = (__bf16)xa[j];
                wb[j] = (__bf16)wa[j];
            }
            *(bf16x4*)&Xt[row][col] = xb;
            *(bf16x4*)&Wt[row][col] = wb;
        }
        __syncthreads();

        #pragma unroll
        for (int ks = 0; ks < BK; ks += 32) {
            bf16x8 af[4], bf[4];
            #pragma unroll
            for (int t = 0; t < 4; ++t) {
                af[t] = *(const bf16x8*)&Xt[wr * 64 + t * 16 + (lane & 15)][ks + (lane >> 4) * 8];
                bf[t] = *(const bf16x8*)&Wt[wc * 64 + t * 16 + (lane & 15)][ks + (lane >> 4) * 8];
            }
            #pragma unroll
            for (int mi = 0; mi < 4; ++mi)
                #pragma unroll
                for (int ni = 0; ni < 4; ++ni)
                    acc[mi][ni] = mfma16(af[mi], bf[ni], acc[mi][ni]);
        }
        __syncthreads();
    }

    const int rbase = (lane >> 4) * 4;
    const int cidx  = lane & 15;
    #pragma unroll
    for (int mi = 0; mi < 4; ++mi) {
        #pragma unroll
        for (int ni = 0; ni < 4; ++ni) {
            const int e = e0 + wc * 64 + ni * 16 + cidx;
            #pragma unroll
            for (int reg = 0; reg < 4; ++reg) {
                const int r = r0 + wr * 64 + mi * 16 + rbase + reg;
                out[(size_t)r * D_DIM + e] = acc[mi][ni][reg];
            }
        }
    }
}

extern "C" void kernel_launch(void* const* d_in, const int* in_sizes, int n_in,
                              void* d_out, int out_size, void* d_ws, size_t ws_size,
                              hipStream_t stream) {
    const float* x    = (const float*)d_in[0];
    const float* keys = (const float*)d_in[2];
    const float* vals = (const float*)d_in[3];
    float* out = (float*)d_out;

    const size_t kvw_bytes = (size_t)D_DIM * D_DIM * sizeof(float);          // 4 MiB
    const size_t kt_bytes  = (size_t)D_DIM * M_DIM * sizeof(__hip_bfloat16); // 128 MiB
    const size_t need      = kvw_bytes + 2 * kt_bytes;

    float* kvw = (float*)d_ws;
    hipMemsetAsync(kvw, 0, kvw_bytes, stream);

    if (ws_size >= need) {
        __hip_bfloat16* KtT = (__hip_bfloat16*)((char*)d_ws + kvw_bytes);
        __hip_bfloat16* VtT = (__hip_bfloat16*)((char*)d_ws + kvw_bytes + kt_bytes);
        convert_tile<<<dim3(M_DIM / 64, D_DIM / 128, 2), dim3(256), 0, stream>>>(
            keys, vals, KtT, VtT);
        kv_gemm8<<<dim3(256), dim3(512), 0, stream>>>(VtT, KtT, kvw);
    } else {
        kv_partial_kernel<<<dim3(64 * NCHUNK), dim3(256), 0, stream>>>(keys, vals, kvw);
    }
    out_gemm_kernel<<<dim3(64, 8), dim3(256), 0, stream>>>(x, kvw, out);
}

// Round 8
// 353.948 us; speedup vs baseline: 1.2361x; 1.0307x over previous
//
#include <hip/hip_runtime.h>
#include <hip/hip_bf16.h>

// out[b,s,e] = sum_d x[b,s,d] * kv[d,e],  kv[d,e] = sum_m keys[m,d]*vals[m,e]
// B*S = 8192, D = 1024, M = 65536. fp32 in/out; internal bf16 MFMA.
//
// Fast path (needs 260 MB ws):
//   1. convert_tile: fp32 [M][D] -> bf16 tiled "LDS-image" layout
//        T[row_tile(8)][m_step(1024)][128 rows][64 m], chunk-swizzle
//        cl = c ^ (row&7) baked in.  FULL-ROW streaming: each block reads
//        64 complete 4KB rows sequentially (DRAM-friendly), 128KB LDS
//        transpose with granule swizzle p = q ^ ((d>>2)&15).
//   2. kv_gemm8: 8-phase 256x256 schedule (T3+T4+T5), 512 thr / 8 waves,
//      BK=64, 2-slot 128KB LDS, gl_lds from contiguous 16KB tiles,
//      XCD-grouped split-K 16, fp32 atomic reduce into kvw[e][d].
//   3. out_gemm: out[r][e] = sum_d x[r][d] * kvw[e][d]

typedef __attribute__((ext_vector_type(8))) __bf16 bf16x8;
typedef __attribute__((ext_vector_type(4))) __bf16 bf16x4;
typedef __attribute__((ext_vector_type(4))) float  f32x4;

#define D_DIM   1024
#define M_DIM   65536
#define ROWS    8192
#define NCHUNK  16
#define MC      (M_DIM / NCHUNK)   // 4096 m per chunk = 64 K-tiles of 64
#define BT      128
#define BK      64
#define LDK     72
#define TILE_BYTES 16384           // one [128 rows][64 m] bf16 tile

__device__ __forceinline__ f32x4 mfma16(bf16x8 a, bf16x8 b, f32x4 c) {
    return __builtin_amdgcn_mfma_f32_16x16x32_bf16(a, b, c, 0, 0, 0);
}

__device__ __forceinline__ void gl_lds16(const void* gsrc, void* ldst) {
    __builtin_amdgcn_global_load_lds(
        (const __attribute__((address_space(1))) unsigned int*)gsrc,
        (__attribute__((address_space(3))) unsigned int*)ldst,
        16, 0, 0);
}

// ---------------------------------------------------------------------------
// Kernel A: fp32 [M][D] -> swizzled bf16 tiles.  Full-row streaming version.
// Block: 64 m x 1024 d (full rows), 512 threads, 128 KB LDS.
// grid = (1024 m-steps, 1, 2 {keys,vals}).
// LDS: row d (0..1023) x 16 granules of 8B (m-quads); phys granule
// p = q ^ ((d>>2)&15).  Output tiles byte-identical to R6/R7 format.
// ---------------------------------------------------------------------------
__global__ __launch_bounds__(512)
void convert_tile(const float* __restrict__ keys,
                  const float* __restrict__ vals,
                  __hip_bfloat16* __restrict__ KtT,
                  __hip_bfloat16* __restrict__ VtT)
{
    __shared__ __align__(16) char Lt[1024 * 128];   // 128 KB

    const float* src = blockIdx.z ? vals : keys;
    char* dstb = (char*)(blockIdx.z ? VtT : KtT);

    const int tid = threadIdx.x;
    const int s   = blockIdx.x;          // m-step (64 m)
    const int m0  = s * 64;

    // ---- phase 1: full-row sequential reads, in-reg 4x4 transpose,
    //      granule-swizzled 8B LDS writes.
    const int dc = tid & 255;            // d-chunk (4 d), all 1024 d
    const int qh = tid >> 8;             // 0..1
    #pragma unroll
    for (int i = 0; i < 8; ++i) {
        const int q = 2 * i + qh;        // m-quad 0..15; block sweeps rows 8i..8i+7
        f32x4 v[4];
        #pragma unroll
        for (int r = 0; r < 4; ++r)
            v[r] = *(const f32x4*)(src + (size_t)(m0 + 4 * q + r) * D_DIM + 4 * dc);
        const int p8 = q ^ (dc & 15);    // phys granule
        #pragma unroll
        for (int j = 0; j < 4; ++j) {
            bf16x4 w;
            #pragma unroll
            for (int r = 0; r < 4; ++r) w[r] = (__bf16)v[r][j];
            *(bf16x4*)(Lt + (4 * dc + j) * 128 + p8 * 8) = w;
        }
    }
    __syncthreads();

    // ---- phase 2: swizzle-resolving 8B reads, coalesced 16B global writes,
    //      emit all 8 d-tiles (output chunk-swizzle cl = c ^ (dl&7) baked in).
    #pragma unroll
    for (int ii = 0; ii < 16; ++ii) {
        const int idx = tid + ii * 512;      // 0..8191 16B-chunks
        const int t   = idx >> 10;           // d-tile 0..7
        const int dl  = (idx >> 3) & 127;    // row in tile
        const int c   = idx & 7;             // phys output chunk
        const int d   = t * 128 + dl;
        const int cl  = c ^ (dl & 7);        // logical chunk (8 m)
        const int h   = (dl >> 2) & 15;      // == (d>>2)&15 (t*32 = 0 mod 16)
        const int g0  = (2 * cl)     ^ h;
        const int g1  = (2 * cl + 1) ^ h;
        bf16x4 lo = *(const bf16x4*)(Lt + d * 128 + g0 * 8);
        bf16x4 hi = *(const bf16x4*)(Lt + d * 128 + g1 * 8);
        bf16x8 w;
        w[0] = lo[0]; w[1] = lo[1]; w[2] = lo[2]; w[3] = lo[3];
        w[4] = hi[0]; w[5] = hi[1]; w[6] = hi[2]; w[7] = hi[3];
        char* dst_tile = dstb + ((size_t)t * 1024 + s) * TILE_BYTES;
        *(bf16x8*)(dst_tile + dl * 128 + c * 16) = w;
    }
}

// ---------------------------------------------------------------------------
// Kernel B: kvw[e][d] += sum_m V[e][m] * K[d][m], tiled operands.
// 8-phase 256x256 template (unchanged from R6).
// ---------------------------------------------------------------------------
__global__ __launch_bounds__(512, 2)
void kv_gemm8(const __hip_bfloat16* __restrict__ VtT,
              const __hip_bfloat16* __restrict__ KtT,
              float* __restrict__ kvw)
{
    __shared__ __align__(16) char lds[2][4][TILE_BYTES];

    const int tid  = threadIdx.x;
    const int lane = tid & 63;
    const int wave = tid >> 6;        // 0..7
    const int we   = wave >> 2;       // 0..1  e-dim (A half)
    const int wd   = wave & 3;        // 0..3  d-dim

    const int bx    = blockIdx.x;
    const int xcd   = bx & 7;
    const int idx   = bx >> 3;                 // 0..31
    const int chunk = ((idx >> 4) << 3) | xcd; // 0..15
    const int t16   = idx & 15;
    const int E8    = t16 >> 2;                // 0..3
    const int D8    = t16 & 3;                 // 0..3

    const size_t step0 = (size_t)chunk * 64;

    const char* Vb = (const char*)VtT;
    const char* Kb = (const char*)KtT;

    const int l15 = lane & 15;
    const int l7  = lane & 7;
    const int hi  = lane >> 4;

    f32x4 acc[8][4] = {};

    auto tileptr = [&](const char* base, int rt, int t) -> const char* {
        return base + ((size_t)rt * 1024 + step0 + (size_t)t) * TILE_BYTES;
    };
    auto stage_sub = [&](int buf, int sub, const char* tile) {
        char* dst = &lds[buf][sub][wave * 1024];
        const char* s = tile + wave * 1024 + lane * 16;
        gl_lds16(s,        dst);
        gl_lds16(s + 8192, dst + 8192);
    };

    stage_sub(0, 0, tileptr(Vb, 2 * E8,     0));
    stage_sub(0, 1, tileptr(Vb, 2 * E8 + 1, 0));
    stage_sub(0, 2, tileptr(Kb, 2 * D8,     0));
    stage_sub(0, 3, tileptr(Kb, 2 * D8 + 1, 0));
    asm volatile("s_waitcnt vmcnt(0)" ::: "memory");
    __builtin_amdgcn_s_barrier();

    bf16x8 bfr[4][2];

    #pragma unroll 2
    for (int t = 0; t < 64; ++t) {
        const int buf = t & 1;
        const char* abase = &lds[buf][we][0];
        const char* bbase = &lds[buf][2 + (wd >> 1)][0];
        const int brow0 = (wd & 1) * 64;

        #pragma unroll
        for (int p = 0; p < 4; ++p) {
            bf16x8 afr[2][2];
            #pragma unroll
            for (int j = 0; j < 2; ++j)
                #pragma unroll
                for (int ks = 0; ks < 2; ++ks) {
                    const int row = (2 * p + j) * 16 + l15;
                    afr[j][ks] = *(const bf16x8*)(abase + row * 128
                                   + (((ks << 2) + hi) ^ l7) * 16);
                }
            if (p == 0) {
                #pragma unroll
                for (int n = 0; n < 4; ++n)
                    #pragma unroll
                    for (int ks = 0; ks < 2; ++ks) {
                        const int row = brow0 + n * 16 + l15;
                        bfr[n][ks] = *(const bf16x8*)(bbase + row * 128
                                       + (((ks << 2) + hi) ^ l7) * 16);
                    }
            }
            if (p == 0 && t + 1 < 64) {
                stage_sub(buf ^ 1, 0, tileptr(Vb, 2 * E8,     t + 1));
                stage_sub(buf ^ 1, 1, tileptr(Vb, 2 * E8 + 1, t + 1));
            }
            if (p == 1 && t + 1 < 64) {
                stage_sub(buf ^ 1, 2, tileptr(Kb, 2 * D8,     t + 1));
                stage_sub(buf ^ 1, 3, tileptr(Kb, 2 * D8 + 1, t + 1));
            }
            __builtin_amdgcn_s_barrier();
            asm volatile("s_waitcnt lgkmcnt(0)" ::: "memory");
            __builtin_amdgcn_sched_barrier(0);
            __builtin_amdgcn_s_setprio(1);
            #pragma unroll
            for (int j = 0; j < 2; ++j)
                #pragma unroll
                for (int n = 0; n < 4; ++n)
                    #pragma unroll
                    for (int ks = 0; ks < 2; ++ks)
                        acc[2 * p + j][n] = mfma16(afr[j][ks], bfr[n][ks],
                                                   acc[2 * p + j][n]);
            __builtin_amdgcn_s_setprio(0);
            if (p == 3)
                asm volatile("s_waitcnt vmcnt(0)" ::: "memory");
            __builtin_amdgcn_s_barrier();
        }
    }

    const int rb = hi * 4;
    #pragma unroll
    for (int mi = 0; mi < 8; ++mi) {
        #pragma unroll
        for (int ni = 0; ni < 4; ++ni) {
            const int d = D8 * 256 + wd * 64 + ni * 16 + l15;
            #pragma unroll
            for (int r = 0; r < 4; ++r) {
                const int e = E8 * 256 + we * 128 + mi * 16 + rb + r;
                atomicAdd(kvw + (size_t)e * D_DIM + d, acc[mi][ni][r]);
            }
        }
    }
}

// ---------------------------------------------------------------------------
// Fallback (ws too small): R1 fused path, known-correct.
// ---------------------------------------------------------------------------
__global__ __launch_bounds__(256)
void kv_partial_kernel(const float* __restrict__ keys,
                       const float* __restrict__ vals,
                       float* __restrict__ kvw)
{
    __shared__ __bf16 Ktl[BT][LDK];
    __shared__ __bf16 Vtl[BT][LDK];

    const int tid  = threadIdx.x;
    const int lane = tid & 63;
    const int wave = tid >> 6;
    const int wr   = wave >> 1;
    const int wc   = wave & 1;

    const int tile  = blockIdx.x & 63;
    const int chunk = blockIdx.x >> 6;
    const int d0 = (tile >> 3) * BT;
    const int e0 = (tile & 7) * BT;
    const size_t mbeg = (size_t)chunk * MC;

    f32x4 acc[4][4] = {};
    const int kg  = tid & 15;
    const int d4a = tid >> 4;

    for (int ms = 0; ms < MC; ms += BK) {
        #pragma unroll
        for (int i = 0; i < 2; ++i) {
            const int dloc = (d4a + i * 16) * 4;
            const size_t mrow = mbeg + ms + (size_t)kg * 4;
            f32x4 kr[4], vr[4];
            #pragma unroll
            for (int r = 0; r < 4; ++r) {
                kr[r] = *(const f32x4*)(keys + (mrow + r) * D_DIM + d0 + dloc);
                vr[r] = *(const f32x4*)(vals + (mrow + r) * D_DIM + e0 + dloc);
            }
            #pragma unroll
            for (int j = 0; j < 4; ++j) {
                bf16x4 wk, wv;
                #pragma unroll
                for (int r = 0; r < 4; ++r) {
                    wk[r] = (__bf16)kr[r][j];
                    wv[r] = (__bf16)vr[r][j];
                }
                *(bf16x4*)&Ktl[dloc + j][kg * 4] = wk;
                *(bf16x4*)&Vtl[dloc + j][kg * 4] = wv;
            }
        }
        __syncthreads();

        #pragma unroll
        for (int ks = 0; ks < BK; ks += 32) {
            bf16x8 af[4], bf[4];
            #pragma unroll
            for (int t = 0; t < 4; ++t) {
                af[t] = *(const bf16x8*)&Ktl[wr * 64 + t * 16 + (lane & 15)][ks + (lane >> 4) * 8];
                bf[t] = *(const bf16x8*)&Vtl[wc * 64 + t * 16 + (lane & 15)][ks + (lane >> 4) * 8];
            }
            #pragma unroll
            for (int mi = 0; mi < 4; ++mi)
                #pragma unroll
                for (int ni = 0; ni < 4; ++ni)
                    acc[mi][ni] = mfma16(af[mi], bf[ni], acc[mi][ni]);
        }
        __syncthreads();
    }

    const int rbase = (lane >> 4) * 4;
    const int cidx  = lane & 15;
    #pragma unroll
    for (int mi = 0; mi < 4; ++mi) {
        #pragma unroll
        for (int ni = 0; ni < 4; ++ni) {
            const int e = e0 + wc * 64 + ni * 16 + cidx;
            #pragma unroll
            for (int reg = 0; reg < 4; ++reg) {
                const int d = d0 + wr * 64 + mi * 16 + rbase + reg;
                atomicAdd(kvw + (size_t)e * D_DIM + d, acc[mi][ni][reg]);
            }
        }
    }
}

// ---------------------------------------------------------------------------
// Kernel C: out[r][e] = sum_d x[r][d] * kvw[e][d]  (unchanged)
// ---------------------------------------------------------------------------
__global__ __launch_bounds__(256)
void out_gemm_kernel(const float* __restrict__ x,
                     const float* __restrict__ kvw,
                     float* __restrict__ out)
{
    __shared__ __bf16 Xt[BT][LDK];
    __shared__ __bf16 Wt[BT][LDK];

    const int tid  = threadIdx.x;
    const int lane = tid & 63;
    const int wave = tid >> 6;
    const int wr   = wave >> 1;
    const int wc   = wave & 1;

    const int r0 = blockIdx.x * BT;
    const int e0 = blockIdx.y * BT;

    f32x4 acc[4][4] = {};

    for (int ks0 = 0; ks0 < D_DIM; ks0 += BK) {
        #pragma unroll
        for (int i = 0; i < 8; ++i) {
            const int idx = tid + i * 256;
            const int row = idx >> 4;
            const int col = (idx & 15) * 4;
            f32x4 xa = *(const f32x4*)(x   + (size_t)(r0 + row) * D_DIM + ks0 + col);
            f32x4 wa = *(const f32x4*)(kvw + (size_t)(e0 + row) * D_DIM + ks0 + col);
            bf16x4 xb, wb;
            #pragma unroll
            for (int j = 0; j < 4; ++j) {
                xb[j] = (__bf16)xa[j];
                wb[j] = (__bf16)wa[j];
            }
            *(bf16x4*)&Xt[row][col] = xb;
            *(bf16x4*)&Wt[row][col] = wb;
        }
        __syncthreads();

        #pragma unroll
        for (int ks = 0; ks < BK; ks += 32) {
            bf16x8 af[4], bf[4];
            #pragma unroll
            for (int t = 0; t < 4; ++t) {
                af[t] = *(const bf16x8*)&Xt[wr * 64 + t * 16 + (lane & 15)][ks + (lane >> 4) * 8];
                bf[t] = *(const bf16x8*)&Wt[wc * 64 + t * 16 + (lane & 15)][ks + (lane >> 4) * 8];
            }
            #pragma unroll
            for (int mi = 0; mi < 4; ++mi)
                #pragma unroll
                for (int ni = 0; ni < 4; ++ni)
                    acc[mi][ni] = mfma16(af[mi], bf[ni], acc[mi][ni]);
        }
        __syncthreads();
    }

    const int rbase = (lane >> 4) * 4;
    const int cidx  = lane & 15;
    #pragma unroll
    for (int mi = 0; mi < 4; ++mi) {
        #pragma unroll
        for (int ni = 0; ni < 4; ++ni) {
            const int e = e0 + wc * 64 + ni * 16 + cidx;
            #pragma unroll
            for (int reg = 0; reg < 4; ++reg) {
                const int r = r0 + wr * 64 + mi * 16 + rbase + reg;
                out[(size_t)r * D_DIM + e] = acc[mi][ni][reg];
            }
        }
    }
}

extern "C" void kernel_launch(void* const* d_in, const int* in_sizes, int n_in,
                              void* d_out, int out_size, void* d_ws, size_t ws_size,
                              hipStream_t stream) {
    const float* x    = (const float*)d_in[0];
    const float* keys = (const float*)d_in[2];
    const float* vals = (const float*)d_in[3];
    float* out = (float*)d_out;

    const size_t kvw_bytes = (size_t)D_DIM * D_DIM * sizeof(float);          // 4 MiB
    const size_t kt_bytes  = (size_t)D_DIM * M_DIM * sizeof(__hip_bfloat16); // 128 MiB
    const size_t need      = kvw_bytes + 2 * kt_bytes;

    float* kvw = (float*)d_ws;
    hipMemsetAsync(kvw, 0, kvw_bytes, stream);

    if (ws_size >= need) {
        __hip_bfloat16* KtT = (__hip_bfloat16*)((char*)d_ws + kvw_bytes);
        __hip_bfloat16* VtT = (__hip_bfloat16*)((char*)d_ws + kvw_bytes + kt_bytes);
        convert_tile<<<dim3(M_DIM / 64, 1, 2), dim3(512), 0, stream>>>(
            keys, vals, KtT, VtT);
        kv_gemm8<<<dim3(256), dim3(512), 0, stream>>>(VtT, KtT, kvw);
    } else {
        kv_partial_kernel<<<dim3(64 * NCHUNK), dim3(256), 0, stream>>>(keys, vals, kvw);
    }
    out_gemm_kernel<<<dim3(64, 8), dim3(256), 0, stream>>>(x, kvw, out);
}